// Round 5
// baseline (582.129 us; speedup 1.0000x reference)
//
#include <hip/hip_runtime.h>
#include <hip/hip_bf16.h>
#include <math.h>

typedef short bf16x8 __attribute__((ext_vector_type(8)));
typedef short bf16x4 __attribute__((ext_vector_type(4)));
typedef float f32x4 __attribute__((ext_vector_type(4)));

#define KDIM 768
#define NTAG 10000
#define NVOC 21128
#define HID 256
#define NTOK 4096
#define NCHUNK 24
#define CHUNK 881                 // ceil(21128/24)
#define NTILE 56                  // ceil(881/16)
#define M0 4.0f                   // fixed softmax shift (logits ~N(0,0.55))

// ws layout (bytes)
#define WS_A     0ull                    // bf16 [4096][768] title
#define WS_AVID  6291456ull              // bf16 [32][768] video (contiguous with A)
#define WS_PSUM  6340608ull              // f32 [4096][24]
#define WS_GOLD  6733824ull              // f32 [4096]
#define WS_TAGL  6750208ull              // f32 [1] (atomic)
#define WS_WM    6750272ull              // bf16 [21128][768]
#define WS_NEED  (WS_WM + 32452608ull + 65536ull)   // + OOB staging pad

#define OUT_EMB  320000
#define OUT_LTAG 328192
#define OUT_LMLM 328193

typedef const __attribute__((address_space(1))) unsigned int glds_g;
typedef __attribute__((address_space(3))) unsigned int glds_l;

static __device__ __forceinline__ unsigned short f2bf(float f) {
  unsigned u = __builtin_bit_cast(unsigned, f);
  u = u + 0x7FFFu + ((u >> 16) & 1u);
  return (unsigned short)(u >> 16);
}

// ---------------- fused f32 -> bf16 conversion (title+video+Wm) ----------------
__global__ __launch_bounds__(256) void k_conv(
    const float* __restrict__ title, const float* __restrict__ video,
    const float* __restrict__ Wm,
    unsigned short* __restrict__ dstA, unsigned short* __restrict__ dstWm) {
  const int nT = 786432;            // title f4 count
  const int nA = 792576;            // +video
  const int nW = 4056576;           // Wm f4 count
  int i = blockIdx.x * 256 + threadIdx.x;
  float4 v;
  unsigned short* dst;
  int di;
  if (i < nA) {
    v = (i < nT) ? ((const float4*)title)[i] : ((const float4*)video)[i - nT];
    dst = dstA; di = i;
  } else {
    int j = i - nA;
    if (j >= nW) return;
    v = ((const float4*)Wm)[j];
    dst = dstWm; di = j;
  }
  bf16x4 o;
  o[0] = (short)f2bf(v.x); o[1] = (short)f2bf(v.y);
  o[2] = (short)f2bf(v.z); o[3] = (short)f2bf(v.w);
  ((bf16x4*)dst)[di] = o;
}

// ---------------- gold logit per token (f32 exact) ----------------
__global__ __launch_bounds__(256) void k_gold(
    const float* __restrict__ title, const int* __restrict__ lab,
    const float* __restrict__ Wm, const float* __restrict__ bm,
    float* __restrict__ gold) {
  int wave = threadIdx.x >> 6, lane = threadIdx.x & 63;
  int tok = blockIdx.x * 4 + wave;
  int l = lab[tok];
  float acc = 0.f;
  #pragma unroll
  for (int j = 0; j < 12; ++j) {
    int k = j * 64 + lane;
    acc += title[(size_t)tok * KDIM + k] * Wm[(size_t)l * KDIM + k];
  }
  #pragma unroll
  for (int m = 32; m; m >>= 1) acc += __shfl_xor(acc, m);
  if (lane == 0) gold[tok] = acc + bm[l];
}

// ---------------- MLM GEMM + streaming sum-exp ----------------
// grid 768: chunk = bid%24 (same-chunk blocks share an XCD: 24%8==0), mt = bid/24
// 256 thr = 4 waves; wave owns 32 token rows; 3 blocks/CU (LDS ~52.9KB).
// LDS B layout: byte = col*16 + g*256 + kk*1024  (reads: 1 base + offset:kk*1024)
template<bool WMBF16>
__global__ __launch_bounds__(256, 3) void k_mlm(
    const unsigned short* __restrict__ A,
    const float* __restrict__ Wm,
    const unsigned short* __restrict__ WmB,
    const float* __restrict__ bm,
    float* __restrict__ psum) {
  __shared__ __align__(16) unsigned short Bsm[2][16 * KDIM];  // 48 KiB dbuf
  __shared__ float biasS[NTILE * 16];                         // 3.5 KiB
  const int tid = threadIdx.x;
  const int lane = tid & 63, g = lane >> 4, col = lane & 15;
  const int wave = tid >> 6;
  const int chunk = blockIdx.x % NCHUNK, mt = blockIdx.x / NCHUNK;
  const int nbeg = chunk * CHUNK;
  const int nend = min(nbeg + CHUNK, NVOC);

  // bias chunk -> LDS
  for (int i = tid; i < NTILE * 16; i += 256) {
    int n = nbeg + i;
    biasS[i] = (n < NVOC) ? bm[n] : 0.f;
  }

  // A fragments (full K in registers)
  const int arow0 = mt * 128 + wave * 32;
  bf16x8 a0[24], a1[24];
  #pragma unroll
  for (int kk = 0; kk < 24; ++kk) {
    a0[kk] = *(const bf16x8*)(A + (size_t)(arow0 + col) * KDIM + kk * 32 + g * 8);
    a1[kk] = *(const bf16x8*)(A + (size_t)(arow0 + 16 + col) * KDIM + kk * 32 + g * 8);
  }

  float s[8];
  #pragma unroll
  for (int i = 0; i < 8; ++i) s[i] = 0.f;

  // staging: slot sigma = j*256+tid holds B row n=sigma&15, k-offset
  // koff = (sigma>>6)*32 + ((sigma>>4)&3)*8  -> source element n*768+koff
  int e[6];
  #pragma unroll
  for (int j = 0; j < 6; ++j) {
    int sg = j * 256 + tid;
    e[j] = (sg & 15) * KDIM + (sg >> 6) * 32 + ((sg >> 4) & 3) * 8;
  }

  const int rbase = col * 16 + g * 256;   // LDS read base (byte)

  auto COMPUTE = [&](int t) {
    const char* B = (const char*)&Bsm[t & 1][0] + rbase;
    f32x4 acc0 = {0.f, 0.f, 0.f, 0.f}, acc1 = {0.f, 0.f, 0.f, 0.f};
    #pragma unroll
    for (int kk = 0; kk < 24; ++kk) {
      bf16x8 b = *(const bf16x8*)(B + kk * 1024);
      acc0 = __builtin_amdgcn_mfma_f32_16x16x32_bf16(a0[kk], b, acc0, 0, 0, 0);
      acc1 = __builtin_amdgcn_mfma_f32_16x16x32_bf16(a1[kk], b, acc1, 0, 0, 0);
    }
    const int n0 = nbeg + t * 16;
    const bool valid = (n0 + col) < nend;
    const float bias = biasS[t * 16 + col];
    #pragma unroll
    for (int rr = 0; rr < 4; ++rr) {
      float x0 = acc0[rr] + bias;
      float x1 = acc1[rr] + bias;
      s[rr]     += valid ? __expf(x0 - M0) : 0.f;
      s[rr + 4] += valid ? __expf(x1 - M0) : 0.f;
    }
  };

  if constexpr (WMBF16) {
    auto STAGE = [&](int buf, int tt) {
      const unsigned short* src = WmB + (size_t)(nbeg + tt * 16) * KDIM;
      char* dst = (char*)&Bsm[buf][0] + wave * 1024;
      #pragma unroll
      for (int j = 0; j < 6; ++j) {
        __builtin_amdgcn_global_load_lds((glds_g*)(src + e[j]),
                                         (glds_l*)(dst + j * 4096), 16, 0, 0);
      }
    };
    STAGE(0, 0);
    asm volatile("s_waitcnt lgkmcnt(0)" ::: "memory");   // bias ds_writes done
    __builtin_amdgcn_s_barrier();
    for (int t = 0; t < NTILE; ++t) {
      int tn = (t + 1 < NTILE) ? t + 1 : 0;
      STAGE((t + 1) & 1, tn);                            // prefetch next tile
      asm volatile("s_waitcnt vmcnt(6)" ::: "memory");   // current tile staged
      __builtin_amdgcn_s_barrier();
      __builtin_amdgcn_sched_barrier(0);
      __builtin_amdgcn_s_setprio(1);
      COMPUTE(t);
      __builtin_amdgcn_s_setprio(0);
      __builtin_amdgcn_sched_barrier(0);
      __builtin_amdgcn_s_barrier();                      // all reads of cur done
    }
  } else {
    // correctness fallback: serial f32 staging with cvt into same layout
    __syncthreads();
    for (int t = 0; t < NTILE; ++t) {
      #pragma unroll
      for (int j = 0; j < 6; ++j) {
        int sg = j * 256 + tid;
        int n = nbeg + t * 16 + (sg & 15);
        int koff = (sg >> 6) * 32 + ((sg >> 4) & 3) * 8;
        float4 v0 = {0.f,0.f,0.f,0.f}, v1 = {0.f,0.f,0.f,0.f};
        if (n < NVOC) {
          v0 = *(const float4*)(Wm + (size_t)n * KDIM + koff);
          v1 = *(const float4*)(Wm + (size_t)n * KDIM + koff + 4);
        }
        bf16x8 o;
        o[0] = (short)f2bf(v0.x); o[1] = (short)f2bf(v0.y);
        o[2] = (short)f2bf(v0.z); o[3] = (short)f2bf(v0.w);
        o[4] = (short)f2bf(v1.x); o[5] = (short)f2bf(v1.y);
        o[6] = (short)f2bf(v1.z); o[7] = (short)f2bf(v1.w);
        *(bf16x8*)((char*)&Bsm[0][0] + sg * 16) = o;
      }
      __syncthreads();
      COMPUTE(t);
      __syncthreads();
    }
  }

  // combine the 16 col-owner lanes per row, write per-chunk partial sums
  #pragma unroll
  for (int i = 0; i < 8; ++i) {
    float v = s[i];
    v += __shfl_xor(v, 1);
    v += __shfl_xor(v, 2);
    v += __shfl_xor(v, 4);
    v += __shfl_xor(v, 8);
    s[i] = v;
  }
  if (col == 0) {
    #pragma unroll
    for (int mblk = 0; mblk < 2; ++mblk)
      #pragma unroll
      for (int rr = 0; rr < 4; ++rr) {
        int tok = arow0 + mblk * 16 + g * 4 + rr;
        psum[tok * NCHUNK + chunk] = s[mblk * 4 + rr];
      }
  }
}

// ---------------- tag head: LDS-free, 1250 independent waves ----------------
__global__ __launch_bounds__(256) void k_tag(
    const unsigned short* __restrict__ Avid,
    const float* __restrict__ Wt, const float* __restrict__ bt,
    const float* __restrict__ ylab,
    float* __restrict__ out_sig, float* __restrict__ tagSum) {
  const int tid = threadIdx.x, lane = tid & 63, g = lane >> 4, col = lane & 15;
  const int wave = tid >> 6;
  const int unit = blockIdx.x * 4 + wave;     // 0..1249
  if (unit >= 1250) return;
  const int ntile = unit >> 1, mhalf = unit & 1;
  const int n0 = ntile * 16;

  bf16x8 a[24];
  #pragma unroll
  for (int kk = 0; kk < 24; ++kk)
    a[kk] = *(const bf16x8*)(Avid + (size_t)(mhalf * 16 + col) * KDIM + kk * 32 + g * 8);

  f32x4 acc = {0.f, 0.f, 0.f, 0.f};
  const float* wrow = Wt + (size_t)(n0 + col) * KDIM;
  #pragma unroll
  for (int kk = 0; kk < 24; ++kk) {
    float4 w0 = *(const float4*)(wrow + kk * 32 + g * 8);
    float4 w1 = *(const float4*)(wrow + kk * 32 + g * 8 + 4);
    bf16x8 b;
    b[0] = (short)f2bf(w0.x); b[1] = (short)f2bf(w0.y);
    b[2] = (short)f2bf(w0.z); b[3] = (short)f2bf(w0.w);
    b[4] = (short)f2bf(w1.x); b[5] = (short)f2bf(w1.y);
    b[6] = (short)f2bf(w1.z); b[7] = (short)f2bf(w1.w);
    acc = __builtin_amdgcn_mfma_f32_16x16x32_bf16(a[kk], b, acc, 0, 0, 0);
  }

  const int nc = n0 + col;
  const float bias = bt[nc];
  float lacc = 0.f;
  #pragma unroll
  for (int rr = 0; rr < 4; ++rr) {
    int brow = mhalf * 16 + g * 4 + rr;
    float x = acc[rr] + bias;
    out_sig[(size_t)brow * NTAG + nc] = 1.f / (1.f + __expf(-x));
    float y = ylab[(size_t)brow * NTAG + nc];
    lacc += fmaxf(x, 0.f) - x * y + log1pf(__expf(-fabsf(x)));
  }
  #pragma unroll
  for (int m = 32; m; m >>= 1) lacc += __shfl_xor(lacc, m);
  if (lane == 0) atomicAdd(tagSum, lacc);
}

// ---------------- embedding head (f32 exact) ----------------
__global__ __launch_bounds__(256) void k_embed(
    const float* __restrict__ video, const float* __restrict__ title,
    const float* __restrict__ Wh, const float* __restrict__ bh,
    float* __restrict__ out_emb) {
  __shared__ float feat[1536];
  __shared__ float red[4];
  const int b = blockIdx.x, tid = threadIdx.x;
  const int wave = tid >> 6, lane = tid & 63;
  #pragma unroll
  for (int j = 0; j < 6; ++j) {
    int k = j * 256 + tid;
    feat[k] = (k < KDIM) ? video[(size_t)b * KDIM + k]
                         : title[(size_t)b * 128 * KDIM + (k - KDIM)];
  }
  __syncthreads();
  float acc = bh[tid];
  #pragma unroll 8
  for (int k = 0; k < 1536; k += 4) {
    float4 w = *(const float4*)(Wh + (size_t)tid * 1536 + k);
    acc += w.x * feat[k] + w.y * feat[k + 1] + w.z * feat[k + 2] + w.w * feat[k + 3];
  }
  float ss = acc * acc;
  #pragma unroll
  for (int m = 32; m; m >>= 1) ss += __shfl_xor(ss, m);
  if (lane == 0) red[wave] = ss;
  __syncthreads();
  float nrm = sqrtf(red[0] + red[1] + red[2] + red[3]);
  float scale = 1.f / fmaxf(nrm, 1e-12f);
  out_emb[(size_t)b * HID + tid] = acc * scale;
}

// ---------------- finalize losses ----------------
__global__ __launch_bounds__(256) void k_final(
    const float* __restrict__ psum, const float* __restrict__ gold,
    const int* __restrict__ lab, const float* __restrict__ tagSum,
    float* __restrict__ out) {
  __shared__ float red[4];
  const int tid = threadIdx.x, wave = tid >> 6, lane = tid & 63;
  if (tid == 0) out[OUT_LTAG] = tagSum[0] / 320000.f;

  float lm = 0.f;
  for (int tok = tid; tok < NTOK; tok += 256) {
    float S = 0.f;
    #pragma unroll
    for (int c = 0; c < NCHUNK; ++c) S += psum[tok * NCHUNK + c];
    float lse = M0 + logf(S);
    if (lab[tok] != 0) lm += lse - gold[tok];
  }
  #pragma unroll
  for (int m = 32; m; m >>= 1) lm += __shfl_xor(lm, m);
  if (lane == 0) red[wave] = lm;
  __syncthreads();
  if (tid == 0) out[OUT_LMLM] = red[0] + red[1] + red[2] + red[3];
}

extern "C" void kernel_launch(void* const* d_in, const int* in_sizes, int n_in,
                              void* d_out, int out_size, void* d_ws, size_t ws_size,
                              hipStream_t stream) {
  const float* video = (const float*)d_in[0];
  const float* title = (const float*)d_in[1];
  const float* ylab  = (const float*)d_in[2];
  const int*   lab   = (const int*)d_in[3];
  const float* Wt = (const float*)d_in[4];
  const float* bt = (const float*)d_in[5];
  const float* Wm = (const float*)d_in[6];
  const float* bm = (const float*)d_in[7];
  const float* Wh = (const float*)d_in[8];
  const float* bh = (const float*)d_in[9];
  float* out = (float*)d_out;
  char* ws = (char*)d_ws;

  unsigned short* wsA    = (unsigned short*)(ws + WS_A);
  unsigned short* wsAvid = (unsigned short*)(ws + WS_AVID);
  float* wsPsum = (float*)(ws + WS_PSUM);
  float* wsGold = (float*)(ws + WS_GOLD);
  float* wsTagl = (float*)(ws + WS_TAGL);
  unsigned short* wsWm = (unsigned short*)(ws + WS_WM);

  const bool useWmB = ws_size >= WS_NEED;

  hipMemsetAsync(wsTagl, 0, 4, stream);
  k_conv<<<18942, 256, 0, stream>>>(title, video, Wm, wsA, wsWm);
  if (useWmB)
    k_mlm<true><<<768, 256, 0, stream>>>(wsA, Wm, wsWm, bm, wsPsum);
  else
    k_mlm<false><<<768, 256, 0, stream>>>(wsA, Wm, wsWm, bm, wsPsum);
  k_tag<<<313, 256, 0, stream>>>(wsAvid, Wt, bt, ylab, out, wsTagl);
  k_gold<<<1024, 256, 0, stream>>>(title, lab, Wm, bm, wsGold);
  k_embed<<<32, 256, 0, stream>>>(video, title, Wh, bh, out + OUT_EMB);
  k_final<<<1, 256, 0, stream>>>(wsPsum, wsGold, lab, wsTagl, out);
}

// Round 6
// 212.479 us; speedup vs baseline: 2.7397x; 2.7397x over previous
//
#include <hip/hip_runtime.h>
#include <hip/hip_bf16.h>
#include <math.h>

typedef short bf16x8 __attribute__((ext_vector_type(8)));
typedef short bf16x4 __attribute__((ext_vector_type(4)));
typedef float f32x4 __attribute__((ext_vector_type(4)));

#define KDIM 768
#define NTAG 10000
#define NVOC 21128
#define HID 256
#define NTOK 4096
#define NCHUNK 24
#define CHUNK 881                 // ceil(21128/24)
#define NTILE 56                  // ceil(881/16)
#define M0 4.0f                   // fixed softmax shift (logits ~N(0,0.55))
#define WMSCALE 16.0f             // Wm pre-scale (fp8 subnormal avoidance)
#define INVSCALE 0.0625f

// ws layout (bytes)
#define WS_A     0ull                    // fp8  [4096][768] title          (3145728)
#define WS_AVID  3145728ull              // bf16 [32][768] video            (49152)
#define WS_PSUM  3194880ull              // f32  [4096][24]                 (393216)
#define WS_GOLD  3588096ull              // f32  [4096]                     (16384)
#define WS_TAGL  3604480ull              // f32  [1] atomic                 (64)
#define WS_WM8   3604544ull              // fp8  [21128][768], x16 scaled   (16226304)
#define WS_NEED  (WS_WM8 + 16226304ull + 65536ull)   // + OOB staging pad

#define OUT_EMB  320000
#define OUT_LTAG 328192
#define OUT_LMLM 328193

typedef const __attribute__((address_space(1))) unsigned int glds_g;
typedef __attribute__((address_space(3))) unsigned int glds_l;

static __device__ __forceinline__ unsigned short f2bf(float f) {
  unsigned u = __builtin_bit_cast(unsigned, f);
  u = u + 0x7FFFu + ((u >> 16) & 1u);
  return (unsigned short)(u >> 16);
}

// pack 4 floats -> 4 fp8 e4m3 bytes
static __device__ __forceinline__ int pk4_fp8(float4 v, float scale) {
  int w = __builtin_amdgcn_cvt_pk_fp8_f32(v.x * scale, v.y * scale, 0, false);
  w = __builtin_amdgcn_cvt_pk_fp8_f32(v.z * scale, v.w * scale, w, true);
  return w;
}

// ---------------- conversions: title->fp8, video->bf16, Wm->fp8(x16) ----------------
__global__ __launch_bounds__(256) void k_conv(
    const float* __restrict__ title, const float* __restrict__ video,
    const float* __restrict__ Wm,
    char* __restrict__ A8, unsigned short* __restrict__ Avid,
    char* __restrict__ Wm8) {
  const int nT = 393216;            // title groups of 8 floats
  const int nV = 3072;              // video groups
  const int nW = 2028288;           // Wm groups
  int i = blockIdx.x * 256 + threadIdx.x;
  if (i < nT) {
    float4 v0 = ((const float4*)title)[i * 2];
    float4 v1 = ((const float4*)title)[i * 2 + 1];
    int2 o = {pk4_fp8(v0, 1.f), pk4_fp8(v1, 1.f)};
    *(int2*)(A8 + (size_t)i * 8) = o;
  } else if (i < nT + nV) {
    int j = i - nT;
    float4 v0 = ((const float4*)video)[j * 2];
    float4 v1 = ((const float4*)video)[j * 2 + 1];
    bf16x8 o;
    o[0] = (short)f2bf(v0.x); o[1] = (short)f2bf(v0.y);
    o[2] = (short)f2bf(v0.z); o[3] = (short)f2bf(v0.w);
    o[4] = (short)f2bf(v1.x); o[5] = (short)f2bf(v1.y);
    o[6] = (short)f2bf(v1.z); o[7] = (short)f2bf(v1.w);
    *(bf16x8*)(Avid + (size_t)j * 8) = o;
  } else {
    int j = i - nT - nV;
    if (j >= nW) return;
    float4 v0 = ((const float4*)Wm)[j * 2];
    float4 v1 = ((const float4*)Wm)[j * 2 + 1];
    int2 o = {pk4_fp8(v0, WMSCALE), pk4_fp8(v1, WMSCALE)};
    *(int2*)(Wm8 + (size_t)j * 8) = o;
  }
}

// ---------------- gold logit per token (f32 exact) ----------------
__global__ __launch_bounds__(256) void k_gold(
    const float* __restrict__ title, const int* __restrict__ lab,
    const float* __restrict__ Wm, const float* __restrict__ bm,
    float* __restrict__ gold) {
  int wave = threadIdx.x >> 6, lane = threadIdx.x & 63;
  int tok = blockIdx.x * 4 + wave;
  int l = lab[tok];
  float acc = 0.f;
  #pragma unroll
  for (int j = 0; j < 12; ++j) {
    int k = j * 64 + lane;
    acc += title[(size_t)tok * KDIM + k] * Wm[(size_t)l * KDIM + k];
  }
  #pragma unroll
  for (int m = 32; m; m >>= 1) acc += __shfl_xor(acc, m);
  if (lane == 0) gold[tok] = acc + bm[l];
}

// ---------------- MLM GEMM (fp8) + streaming sum-exp ----------------
// grid 768: chunk = bid%24 (same-chunk blocks share an XCD), mt = bid/24
// 256 thr = 4 waves; wave owns 32 rows (a0/a1 = 96 VGPR fp8); 3 blocks/CU pinned.
// LDS B tile (fp8, 12KB): byte = kk2*1024 + col*64 + (koff ^ (((col>>1)&3)<<4))
//   koff = (kk&1)*32 + g*8 ; swizzle granule = 16B so global_load_lds stays contiguous.
template<bool WM8>
__global__ __launch_bounds__(256)
__attribute__((amdgpu_waves_per_eu(3, 3)))
void k_mlm(
    const char* __restrict__ A8,
    const float* __restrict__ Wm,
    const char* __restrict__ Wm8,
    const float* __restrict__ bm,
    float* __restrict__ psum) {
  __shared__ __align__(16) char Bsm[2][16 * KDIM];            // 24 KiB dbuf (fp8)
  __shared__ float biasS[NTILE * 16];                         // 3.5 KiB
  const int tid = threadIdx.x;
  const int lane = tid & 63, g = lane >> 4, col = lane & 15;
  const int wave = tid >> 6;
  const int chunk = blockIdx.x % NCHUNK, mt = blockIdx.x / NCHUNK;
  const int nbeg = chunk * CHUNK;
  const int nend = min(nbeg + CHUNK, NVOC);

  // bias chunk -> LDS
  for (int i = tid; i < NTILE * 16; i += 256) {
    int n = nbeg + i;
    biasS[i] = (n < NVOC) ? bm[n] : 0.f;
  }

  // A fragments (full K in registers, fp8: 2 VGPR each)
  const int arow0 = mt * 128 + wave * 32;
  long a0[24], a1[24];
  #pragma unroll
  for (int kk = 0; kk < 24; ++kk) {
    a0[kk] = *(const long*)(A8 + (size_t)(arow0 + col) * KDIM + kk * 32 + g * 8);
    a1[kk] = *(const long*)(A8 + (size_t)(arow0 + 16 + col) * KDIM + kk * 32 + g * 8);
  }

  float s[8];
  #pragma unroll
  for (int i = 0; i < 8; ++i) s[i] = 0.f;

  // staging source offsets: slot sg = j*256+tid (16B each)
  // kk2=sg/64, n_local=(sg>>2)&15, q=sg&3, q'=q^((n_local>>1)&3)
  int e[3];
  #pragma unroll
  for (int j = 0; j < 3; ++j) {
    int sg = j * 256 + tid;
    int kk2 = sg >> 6, nl = (sg >> 2) & 15, q = sg & 3;
    int qp = q ^ ((nl >> 1) & 3);
    e[j] = nl * KDIM + kk2 * 64 + qp * 16;
  }

  const int off0 = col * 64 + ((g * 8) ^ (((col >> 1) & 3) << 4));

  auto COMPUTE = [&](int t) {
    const char* Bb = &Bsm[t & 1][0];
    const char* B0 = Bb + off0;
    const char* B1 = Bb + (off0 ^ 32);
    f32x4 acc0 = {0.f, 0.f, 0.f, 0.f}, acc1 = {0.f, 0.f, 0.f, 0.f};
    #pragma unroll
    for (int kk = 0; kk < 24; ++kk) {
      long b = *(const long*)(((kk & 1) ? B1 : B0) + (kk >> 1) * 1024);
      acc0 = __builtin_amdgcn_mfma_f32_16x16x32_fp8_fp8(a0[kk], b, acc0, 0, 0, 0);
      acc1 = __builtin_amdgcn_mfma_f32_16x16x32_fp8_fp8(a1[kk], b, acc1, 0, 0, 0);
    }
    const int n0 = nbeg + t * 16;
    const bool valid = (n0 + col) < nend;
    const float bias = biasS[t * 16 + col];
    #pragma unroll
    for (int rr = 0; rr < 4; ++rr) {
      float x0 = acc0[rr] * INVSCALE + bias;
      float x1 = acc1[rr] * INVSCALE + bias;
      s[rr]     += valid ? __expf(x0 - M0) : 0.f;
      s[rr + 4] += valid ? __expf(x1 - M0) : 0.f;
    }
  };

  if constexpr (WM8) {
    auto STAGE = [&](int buf, int tt) {
      const char* src = Wm8 + (size_t)(nbeg + tt * 16) * KDIM;
      char* dst = &Bsm[buf][0] + wave * 1024;
      #pragma unroll
      for (int j = 0; j < 3; ++j) {
        __builtin_amdgcn_global_load_lds((glds_g*)(src + e[j]),
                                         (glds_l*)(dst + j * 4096), 16, 0, 0);
      }
    };
    STAGE(0, 0);
    asm volatile("s_waitcnt lgkmcnt(0)" ::: "memory");   // bias ds_writes done
    __builtin_amdgcn_s_barrier();
    for (int t = 0; t < NTILE; ++t) {
      int tn = (t + 1 < NTILE) ? t + 1 : 0;
      STAGE((t + 1) & 1, tn);                            // prefetch next tile
      asm volatile("s_waitcnt vmcnt(3)" ::: "memory");   // current tile staged
      __builtin_amdgcn_s_barrier();
      __builtin_amdgcn_sched_barrier(0);
      __builtin_amdgcn_s_setprio(1);
      COMPUTE(t);
      __builtin_amdgcn_s_setprio(0);
      __builtin_amdgcn_sched_barrier(0);
      __builtin_amdgcn_s_barrier();                      // all reads of cur done
    }
  } else {
    // fallback: serial staging from f32 Wm with inline fp8 cvt (x16)
    __syncthreads();
    for (int t = 0; t < NTILE; ++t) {
      #pragma unroll
      for (int j = 0; j < 3; ++j) {
        int sg = j * 256 + tid;
        int kk2 = sg >> 6, nl = (sg >> 2) & 15, q = sg & 3;
        int qp = q ^ ((nl >> 1) & 3);
        int n = nbeg + t * 16 + nl;
        int4 o = {0, 0, 0, 0};
        if (n < NVOC) {
          const float* wp = Wm + (size_t)n * KDIM + kk2 * 64 + qp * 16;
          float4 f0 = ((const float4*)wp)[0], f1 = ((const float4*)wp)[1];
          float4 f2 = ((const float4*)wp)[2], f3 = ((const float4*)wp)[3];
          o.x = pk4_fp8(f0, WMSCALE); o.y = pk4_fp8(f1, WMSCALE);
          o.z = pk4_fp8(f2, WMSCALE); o.w = pk4_fp8(f3, WMSCALE);
        }
        *(int4*)(&Bsm[0][0] + sg * 16) = o;
      }
      __syncthreads();
      COMPUTE(t);
      __syncthreads();
    }
  }

  // combine the 16 col-owner lanes per row, write per-chunk partial sums
  #pragma unroll
  for (int i = 0; i < 8; ++i) {
    float v = s[i];
    v += __shfl_xor(v, 1);
    v += __shfl_xor(v, 2);
    v += __shfl_xor(v, 4);
    v += __shfl_xor(v, 8);
    s[i] = v;
  }
  if (col == 0) {
    #pragma unroll
    for (int mblk = 0; mblk < 2; ++mblk)
      #pragma unroll
      for (int rr = 0; rr < 4; ++rr) {
        int tok = arow0 + mblk * 16 + g * 4 + rr;
        psum[tok * NCHUNK + chunk] = s[mblk * 4 + rr];
      }
  }
}

// ---------------- tag head: LDS-free, 1250 independent waves (bf16) ----------------
__global__ __launch_bounds__(256) void k_tag(
    const unsigned short* __restrict__ Avid,
    const float* __restrict__ Wt, const float* __restrict__ bt,
    const float* __restrict__ ylab,
    float* __restrict__ out_sig, float* __restrict__ tagSum) {
  const int tid = threadIdx.x, lane = tid & 63, g = lane >> 4, col = lane & 15;
  const int wave = tid >> 6;
  const int unit = blockIdx.x * 4 + wave;     // 0..1249
  if (unit >= 1250) return;
  const int ntile = unit >> 1, mhalf = unit & 1;
  const int n0 = ntile * 16;

  bf16x8 a[24];
  #pragma unroll
  for (int kk = 0; kk < 24; ++kk)
    a[kk] = *(const bf16x8*)(Avid + (size_t)(mhalf * 16 + col) * KDIM + kk * 32 + g * 8);

  f32x4 acc = {0.f, 0.f, 0.f, 0.f};
  const float* wrow = Wt + (size_t)(n0 + col) * KDIM;
  #pragma unroll
  for (int kk = 0; kk < 24; ++kk) {
    float4 w0 = *(const float4*)(wrow + kk * 32 + g * 8);
    float4 w1 = *(const float4*)(wrow + kk * 32 + g * 8 + 4);
    bf16x8 b;
    b[0] = (short)f2bf(w0.x); b[1] = (short)f2bf(w0.y);
    b[2] = (short)f2bf(w0.z); b[3] = (short)f2bf(w0.w);
    b[4] = (short)f2bf(w1.x); b[5] = (short)f2bf(w1.y);
    b[6] = (short)f2bf(w1.z); b[7] = (short)f2bf(w1.w);
    acc = __builtin_amdgcn_mfma_f32_16x16x32_bf16(a[kk], b, acc, 0, 0, 0);
  }

  const int nc = n0 + col;
  const float bias = bt[nc];
  float lacc = 0.f;
  #pragma unroll
  for (int rr = 0; rr < 4; ++rr) {
    int brow = mhalf * 16 + g * 4 + rr;
    float x = acc[rr] + bias;
    out_sig[(size_t)brow * NTAG + nc] = 1.f / (1.f + __expf(-x));
    float y = ylab[(size_t)brow * NTAG + nc];
    lacc += fmaxf(x, 0.f) - x * y + log1pf(__expf(-fabsf(x)));
  }
  #pragma unroll
  for (int m = 32; m; m >>= 1) lacc += __shfl_xor(lacc, m);
  if (lane == 0) atomicAdd(tagSum, lacc);
}

// ---------------- embedding head (f32 exact) ----------------
__global__ __launch_bounds__(256) void k_embed(
    const float* __restrict__ video, const float* __restrict__ title,
    const float* __restrict__ Wh, const float* __restrict__ bh,
    float* __restrict__ out_emb) {
  __shared__ float feat[1536];
  __shared__ float red[4];
  const int b = blockIdx.x, tid = threadIdx.x;
  const int wave = tid >> 6, lane = tid & 63;
  #pragma unroll
  for (int j = 0; j < 6; ++j) {
    int k = j * 256 + tid;
    feat[k] = (k < KDIM) ? video[(size_t)b * KDIM + k]
                         : title[(size_t)b * 128 * KDIM + (k - KDIM)];
  }
  __syncthreads();
  float acc = bh[tid];
  #pragma unroll 8
  for (int k = 0; k < 1536; k += 4) {
    float4 w = *(const float4*)(Wh + (size_t)tid * 1536 + k);
    acc += w.x * feat[k] + w.y * feat[k + 1] + w.z * feat[k + 2] + w.w * feat[k + 3];
  }
  float ss = acc * acc;
  #pragma unroll
  for (int m = 32; m; m >>= 1) ss += __shfl_xor(ss, m);
  if (lane == 0) red[wave] = ss;
  __syncthreads();
  float nrm = sqrtf(red[0] + red[1] + red[2] + red[3]);
  float scale = 1.f / fmaxf(nrm, 1e-12f);
  out_emb[(size_t)b * HID + tid] = acc * scale;
}

// ---------------- finalize losses ----------------
__global__ __launch_bounds__(256) void k_final(
    const float* __restrict__ psum, const float* __restrict__ gold,
    const int* __restrict__ lab, const float* __restrict__ tagSum,
    float* __restrict__ out) {
  __shared__ float red[4];
  const int tid = threadIdx.x, wave = tid >> 6, lane = tid & 63;
  if (tid == 0) out[OUT_LTAG] = tagSum[0] / 320000.f;

  float lm = 0.f;
  for (int tok = tid; tok < NTOK; tok += 256) {
    float S = 0.f;
    #pragma unroll
    for (int c = 0; c < NCHUNK; ++c) S += psum[tok * NCHUNK + c];
    float lse = M0 + logf(S);
    if (lab[tok] != 0) lm += lse - gold[tok];
  }
  #pragma unroll
  for (int m = 32; m; m >>= 1) lm += __shfl_xor(lm, m);
  if (lane == 0) red[wave] = lm;
  __syncthreads();
  if (tid == 0) out[OUT_LMLM] = red[0] + red[1] + red[2] + red[3];
}

extern "C" void kernel_launch(void* const* d_in, const int* in_sizes, int n_in,
                              void* d_out, int out_size, void* d_ws, size_t ws_size,
                              hipStream_t stream) {
  const float* video = (const float*)d_in[0];
  const float* title = (const float*)d_in[1];
  const float* ylab  = (const float*)d_in[2];
  const int*   lab   = (const int*)d_in[3];
  const float* Wt = (const float*)d_in[4];
  const float* bt = (const float*)d_in[5];
  const float* Wm = (const float*)d_in[6];
  const float* bm = (const float*)d_in[7];
  const float* Wh = (const float*)d_in[8];
  const float* bh = (const float*)d_in[9];
  float* out = (float*)d_out;
  char* ws = (char*)d_ws;

  char* wsA8   = ws + WS_A;
  unsigned short* wsAvid = (unsigned short*)(ws + WS_AVID);
  float* wsPsum = (float*)(ws + WS_PSUM);
  float* wsGold = (float*)(ws + WS_GOLD);
  float* wsTagl = (float*)(ws + WS_TAGL);
  char* wsWm8  = ws + WS_WM8;

  const bool useWm8 = ws_size >= WS_NEED;

  hipMemsetAsync(wsTagl, 0, 4, stream);
  k_conv<<<9471, 256, 0, stream>>>(title, video, Wm, wsA8, wsAvid, wsWm8);
  if (useWm8)
    k_mlm<true><<<768, 256, 0, stream>>>(wsA8, Wm, wsWm8, bm, wsPsum);
  else
    k_mlm<false><<<768, 256, 0, stream>>>(wsA8, Wm, wsWm8, bm, wsPsum);
  k_tag<<<313, 256, 0, stream>>>(wsAvid, Wt, bt, ylab, out, wsTagl);
  k_gold<<<1024, 256, 0, stream>>>(title, lab, Wm, bm, wsGold);
  k_embed<<<32, 256, 0, stream>>>(video, title, Wh, bh, out + OUT_EMB);
  k_final<<<1, 256, 0, stream>>>(wsPsum, wsGold, lab, wsTagl, out);
}